// Round 13
// baseline (351.590 us; speedup 1.0000x reference)
//
#include <hip/hip_runtime.h>
#include <math.h>

// Problem constants
constexpr int B_   = 128;
constexpr int N_   = 1024;
constexpr int E_   = 1048576;
constexpr int BN_  = B_ * N_;     // 131072
constexpr int EPG  = E_ / B_;     // 8192 edges per graph (contiguous, fixed)
constexpr int NSEG = 16;          // readout segments per graph

typedef short v8s __attribute__((ext_vector_type(8)));
typedef float v4f __attribute__((ext_vector_type(4)));

__device__ __forceinline__ unsigned bf16_rne(unsigned u) {
    return (u + 0x7FFFu + ((u >> 16) & 1u)) >> 16;
}

// ---------------- per-graph CSR build from ORIGINAL edges + cumulative map ----------------
// cum==NULL: identity (layer 0). Emits srt (src ids grouped by dst), rowptr,
// dis = rsqrt(deg+1). 1 block per graph.
__global__ __launch_bounds__(1024) void k_csr2(
        const int* __restrict__ src, const int* __restrict__ dst,
        const int* __restrict__ cum,
        int* __restrict__ srt, int* __restrict__ rowptr,
        float* __restrict__ dis, int n) {
    __shared__ int cnt[1024];
    __shared__ int cur[1024];
    __shared__ int cums[1024];
    __shared__ int wsum[17];
    int g = blockIdx.x, tid = threadIdx.x;
    int gb   = g * N_;            // original node base
    int base = g * n;             // current node base
    const int eb = g * EPG;

    cums[tid] = cum ? cum[gb + tid] : tid;
    cnt[tid] = 0;
    __syncthreads();
    for (int t = tid; t < EPG; t += 1024) {
        int s = cums[src[eb + t] - gb];
        int d = cums[dst[eb + t] - gb];
        if ((s | d) >= 0) atomicAdd(&cnt[d], 1);
    }
    __syncthreads();

    int c = (tid < n) ? cnt[tid] : 0;
    int v = c;
    int lane = tid & 63, wv = tid >> 6;
    #pragma unroll
    for (int off = 1; off < 64; off <<= 1) {
        int t = __shfl_up(v, off, 64);
        if (lane >= off) v += t;
    }
    if (lane == 63) wsum[wv] = v;
    __syncthreads();
    if (tid == 0) {
        int run = 0;
        #pragma unroll
        for (int i = 0; i < 16; ++i) { int t = wsum[i]; wsum[i] = run; run += t; }
        wsum[16] = run;
    }
    __syncthreads();
    int excl = v - c + wsum[wv];
    if (tid < n) {
        cur[tid] = excl;
        rowptr[g * (n + 1) + tid] = excl;
        dis[base + tid] = rsqrtf((float)c + 1.0f);
    }
    if (tid == 0) rowptr[g * (n + 1) + n] = wsum[16];
    __syncthreads();

    for (int t = tid; t < EPG; t += 1024) {
        int s = cums[src[eb + t] - gb];
        int d = cums[dst[eb + t] - gb];
        if ((s | d) < 0) continue;
        int pos = atomicAdd(&cur[d], 1);
        srt[eb + pos] = s;
    }
}

// ---------------- W fragment prep for all 3 layers ----------------
__global__ __launch_bounds__(1024) void k_wprep3(
        const float* __restrict__ W0, const float* __restrict__ W1,
        const float* __restrict__ W2, unsigned short* __restrict__ wfall) {
    const float* W = (blockIdx.x == 0) ? W0 : (blockIdx.x == 1) ? W1 : W2;
    unsigned short* wf = wfall + (size_t)blockIdx.x * 8192;
    int t = threadIdx.x;
    int l  = t & 63;
    int kk = (t >> 6) & 1;
    int c  = (t >> 7) & 3;
    int p  = (t >> 9) & 1;
    int col = c * 16 + (l & 15);
    int kbase = kk * 32 + (l >> 4) * 8;
    unsigned short o[8];
    #pragma unroll
    for (int j = 0; j < 8; ++j) {
        float w = W[(kbase + j) * 64 + col];
        unsigned u  = __float_as_uint(w);
        unsigned hi = bf16_rne(u);
        if (p == 0) o[j] = (unsigned short)hi;
        else {
            float lo = w - __uint_as_float(hi << 16);
            o[j] = (unsigned short)bf16_rne(__float_as_uint(lo));
        }
    }
    uint4 v;
    v.x = o[0] | ((unsigned)o[1] << 16);
    v.y = o[2] | ((unsigned)o[3] << 16);
    v.z = o[4] | ((unsigned)o[5] << 16);
    v.w = o[6] | ((unsigned)o[7] << 16);
    *reinterpret_cast<uint4*>(wf + (size_t)t * 8) = v;
}

// ---------------- xws = (gather(h)*gate @ W) * dis via split-bf16 MFMA ----------------
// perm==NULL: direct rows (layer 0). Output ROW-MAJOR: xw[row*64 + col].
__global__ __launch_bounds__(256) void k_xw_mfma(
        const float* __restrict__ h, const int* __restrict__ perm,
        const float* __restrict__ ggate, const unsigned short* __restrict__ wf,
        const float* __restrict__ dis, float* __restrict__ xw, int rows) {
    __shared__ float hs[128][68];
    __shared__ float sdis[128];
    __shared__ int   lperm[128];
    __shared__ float lgate[128];
    int tid = threadIdx.x;
    int r0 = blockIdx.x * 128;

    if (perm) {
        if (tid < 128) { lperm[tid] = perm[r0 + tid]; lgate[tid] = ggate[r0 + tid]; }
        __syncthreads();
        for (int i = tid; i < 128 * 16; i += 256) {
            int row = i >> 4, s = i & 15;
            float4 v = *reinterpret_cast<const float4*>(h + (size_t)lperm[row] * 64 + s * 4);
            float gt = lgate[row];
            v.x *= gt; v.y *= gt; v.z *= gt; v.w *= gt;
            *reinterpret_cast<float4*>(&hs[row][s * 4]) = v;
        }
    } else {
        for (int i = tid; i < 128 * 16; i += 256) {
            int row = i >> 4, s = i & 15;
            float4 v = *reinterpret_cast<const float4*>(h + (size_t)(r0 + row) * 64 + s * 4);
            *reinterpret_cast<float4*>(&hs[row][s * 4]) = v;
        }
    }
    if (tid < 128) sdis[tid] = dis[r0 + tid];

    int lane = tid & 63;
    v8s wh[4][2], wl[4][2];
    #pragma unroll
    for (int c = 0; c < 4; ++c) {
        #pragma unroll
        for (int kk = 0; kk < 2; ++kk) {
            wh[c][kk] = *reinterpret_cast<const v8s*>(wf + (((size_t)((0*4 + c)*2 + kk))*64 + lane)*8);
            wl[c][kk] = *reinterpret_cast<const v8s*>(wf + (((size_t)((1*4 + c)*2 + kk))*64 + lane)*8);
        }
    }
    __syncthreads();

    int wave = tid >> 6;
    int m = lane & 15, b = lane >> 4;
    #pragma unroll
    for (int t = 0; t < 2; ++t) {
        int lr0 = (wave * 2 + t) * 16;
        float f[16];
        *reinterpret_cast<float4*>(f)      = *reinterpret_cast<const float4*>(&hs[lr0 + m][b * 8]);
        *reinterpret_cast<float4*>(f + 4)  = *reinterpret_cast<const float4*>(&hs[lr0 + m][b * 8 + 4]);
        *reinterpret_cast<float4*>(f + 8)  = *reinterpret_cast<const float4*>(&hs[lr0 + m][32 + b * 8]);
        *reinterpret_cast<float4*>(f + 12) = *reinterpret_cast<const float4*>(&hs[lr0 + m][32 + b * 8 + 4]);
        v8s ah[2], al[2];
        #pragma unroll
        for (int ch = 0; ch < 2; ++ch) {
            #pragma unroll
            for (int j = 0; j < 8; ++j) {
                float x = f[ch * 8 + j];
                unsigned u  = __float_as_uint(x);
                unsigned hi = bf16_rne(u);
                float lo = x - __uint_as_float(hi << 16);
                ah[ch][j] = (short)hi;
                al[ch][j] = (short)bf16_rne(__float_as_uint(lo));
            }
        }
        float dv[4];
        #pragma unroll
        for (int reg = 0; reg < 4; ++reg) dv[reg] = sdis[lr0 + b * 4 + reg];

        #pragma unroll
        for (int c = 0; c < 4; ++c) {
            v4f acc = {0.f, 0.f, 0.f, 0.f};
            acc = __builtin_amdgcn_mfma_f32_16x16x32_bf16(ah[0], wh[c][0], acc, 0, 0, 0);
            acc = __builtin_amdgcn_mfma_f32_16x16x32_bf16(ah[1], wh[c][1], acc, 0, 0, 0);
            acc = __builtin_amdgcn_mfma_f32_16x16x32_bf16(al[0], wh[c][0], acc, 0, 0, 0);
            acc = __builtin_amdgcn_mfma_f32_16x16x32_bf16(al[1], wh[c][1], acc, 0, 0, 0);
            acc = __builtin_amdgcn_mfma_f32_16x16x32_bf16(ah[0], wl[c][0], acc, 0, 0, 0);
            acc = __builtin_amdgcn_mfma_f32_16x16x32_bf16(ah[1], wl[c][1], acc, 0, 0, 0);
            acc = __builtin_amdgcn_mfma_f32_16x16x32_bf16(al[0], wl[c][0], acc, 0, 0, 0);
            acc = __builtin_amdgcn_mfma_f32_16x16x32_bf16(al[1], wl[c][1], acc, 0, 0, 0);
            #pragma unroll
            for (int reg = 0; reg < 4; ++reg) {
                int grow = r0 + lr0 + b * 4 + reg;
                xw[(size_t)grow * 64 + c * 16 + m] = acc[reg] * dv[reg];
            }
        }
    }
}

// ---------------- row-per-wave coalesced global gather aggregation ----------------
// block = (graph, row-quarter): g = blockIdx&127, quarter = blockIdx>>7
// (same-XCD quarters -> xw slice L2-resident). Wave processes one dst row at a
// time: lane = feature, each edge = one coalesced 256B read xw[src][0..63].
// No LDS, no divergence (loop bounds wave-uniform). Epilogue: bias+ReLU -> hout,
// score dot via shfl reduce -> ps.
__global__ __launch_bounds__(1024) void k_agg_gather(
        const int* __restrict__ srt, const int* __restrict__ rowptr,
        const float* __restrict__ dis, const float* __restrict__ xw,
        const float* __restrict__ bias, const float* __restrict__ Wp,
        float* __restrict__ hout, float* __restrict__ ps, int n) {
    int g = blockIdx.x & 127, quarter = blockIdx.x >> 7;
    int tid = threadIdx.x, lane = tid & 63, wave = tid >> 6;
    int base = g * n;
    int nq  = (n + 3) >> 2;               // rows per quarter
    int rpw = (nq + 15) >> 4;             // rows per wave
    int r0 = quarter * nq + wave * rpw;
    int r1 = min(min(r0 + rpw, (quarter + 1) * nq), n);

    float bq  = bias[lane];
    float wpl = Wp[lane];
    const float* xg  = xw + (size_t)base * 64;
    const int* gsrt  = srt + g * EPG;
    const int* grp   = rowptr + g * (n + 1);

    for (int r = r0; r < r1; ++r) {
        int s0 = grp[r], s1 = grp[r + 1];          // wave-uniform
        float acc = xg[(size_t)r * 64 + lane];     // self-loop (xw pre-scaled)
        for (int j = s0; j < s1; ++j) {
            int src = gsrt[j];                     // wave-uniform broadcast
            acc += xg[(size_t)src * 64 + lane];    // coalesced 256B
        }
        float dsc = dis[base + r];
        float o = fmaxf(fmaf(dsc, acc, bq), 0.0f);
        hout[(size_t)(base + r) * 64 + lane] = o;
        float part = o * wpl;
        #pragma unroll
        for (int off = 32; off; off >>= 1) part += __shfl_xor(part, off, 64);
        if (lane == 0) ps[base + r] = part * dsc;  // score message (pre-scaled)
    }
}

// ---------------- score aggregation + top-k + gates + cum update ----------------
__global__ __launch_bounds__(1024) void k_score_topk(
        const int* __restrict__ srt, const int* __restrict__ rowptr,
        const float* __restrict__ dis, const float* __restrict__ ps,
        const float* __restrict__ bp, int n, int k,
        int* __restrict__ perm, float* __restrict__ ggate,
        int* __restrict__ cum, int do_compose) {
    __shared__ float psl[1024];
    __shared__ unsigned long long keys[1024];
    __shared__ int mark[1024];
    int g = blockIdx.x, tid = threadIdx.x;
    int base = g * n;
    float bp0 = bp[0];
    const int* gsrt = srt + g * EPG;
    const int* grp  = rowptr + g * (n + 1);

    psl[tid] = (tid < n) ? ps[base + tid] : 0.0f;
    __syncthreads();

    unsigned long long kv = 0ull;
    if (tid < n) {
        float acc = psl[tid];                      // self loop
        int s1 = grp[tid + 1];
        for (int j = grp[tid]; j < s1; ++j) acc += psl[gsrt[j]];
        float sag = dis[base + tid] * acc + bp0;
        unsigned u  = __float_as_uint(sag);
        unsigned mk = (u & 0x80000000u) ? ~u : (u | 0x80000000u);
        kv = ((unsigned long long)mk << 32) | (unsigned)tid;
    }
    keys[tid] = kv;
    mark[tid] = -1;

    for (int size = 2; size <= 1024; size <<= 1) {
        for (int stride = size >> 1; stride > 0; stride >>= 1) {
            __syncthreads();
            if (tid < 512) {
                int a  = ((tid / stride) * (stride << 1)) + (tid & (stride - 1));
                int bx = a + stride;
                bool asc = ((a & size) == 0);
                unsigned long long ka = keys[a], kb = keys[bx];
                bool sw = asc ? (ka > kb) : (ka < kb);
                if (sw) { keys[a] = kb; keys[bx] = ka; }
            }
        }
    }
    __syncthreads();

    if (tid < k) {
        int j = tid;
        unsigned long long kvv = keys[1023 - j];
        int local   = (int)(kvv & 0xFFFFFFFFull);
        unsigned mk = (unsigned)(kvv >> 32);
        unsigned u  = (mk & 0x80000000u) ? (mk ^ 0x80000000u) : ~mk;
        int newg = g * k + j;
        perm[newg]  = base + local;
        ggate[newg] = tanhf(__uint_as_float(u));
        mark[local] = j;
    }
    __syncthreads();
    if (do_compose) {
        int gb = g * N_;
        int c = (do_compose == 1) ? tid : cum[gb + tid];
        cum[gb + tid] = (c >= 0) ? mark[c] : -1;
    }
}

// ---------------- segmented readout (max + sum partials), no materialization ----------------
__global__ __launch_bounds__(256) void k_readout_seg(
        const float* __restrict__ h, const int* __restrict__ perm,
        const float* __restrict__ ggate, int k, float* __restrict__ pz) {
    int g = blockIdx.x / NSEG, seg = blockIdx.x % NSEG;
    int ck = (k + NSEG - 1) / NSEG;
    int j0 = seg * ck;
    int j1 = min(k, j0 + ck);
    __shared__ float gate[64];
    __shared__ int   lperm[64];
    int tid = threadIdx.x;
    for (int j = j0 + tid; j < j1; j += 256) {
        lperm[j - j0] = perm[g * k + j];
        gate[j - j0]  = ggate[g * k + j];
    }
    __syncthreads();
    int lane = tid & 63, w = tid >> 6;
    float mx = -INFINITY, sm = 0.0f;
    for (int j = j0 + w; j < j1; j += 4) {
        float v = h[(size_t)lperm[j - j0] * 64 + lane] * gate[j - j0];
        mx = fmaxf(mx, v); sm += v;
    }
    __shared__ float smx[4][64], ssm[4][64];
    smx[w][lane] = mx; ssm[w][lane] = sm;
    __syncthreads();
    if (w == 0) {
        #pragma unroll
        for (int i = 1; i < 4; ++i) { mx = fmaxf(mx, smx[i][lane]); sm += ssm[i][lane]; }
        float* p = pz + ((size_t)g * NSEG + seg) * 128;
        p[lane]      = mx;
        p[64 + lane] = sm;
    }
}

// ---------------- MLP head: reduce pz over layers/segments + log_softmax ----------------
__global__ __launch_bounds__(128) void k_mlp(const float* __restrict__ pz,
                      const float* __restrict__ L1w, const float* __restrict__ L1b,
                      const float* __restrict__ L2w, const float* __restrict__ L2b,
                      const float* __restrict__ L3w, const float* __restrict__ L3b,
                      float* __restrict__ out) {
    __shared__ float z[128], h1[64], h2[32], lg[10], lse;
    int g = blockIdx.x, tid = threadIdx.x;
    const float kinv[3] = {1.0f / 820.0f, 1.0f / 656.0f, 1.0f / 525.0f};
    float zv = 0.0f;
    if (tid < 64) {
        #pragma unroll
        for (int L = 0; L < 3; ++L) {
            const float* p = pz + (((size_t)L * B_ + g) * NSEG) * 128;
            float mx = -INFINITY;
            #pragma unroll
            for (int s = 0; s < NSEG; ++s) mx = fmaxf(mx, p[s * 128 + tid]);
            zv += mx;
        }
    } else {
        int f = tid - 64;
        #pragma unroll
        for (int L = 0; L < 3; ++L) {
            const float* p = pz + (((size_t)L * B_ + g) * NSEG) * 128;
            float sm = 0.0f;
            #pragma unroll
            for (int s = 0; s < NSEG; ++s) sm += p[s * 128 + 64 + f];
            zv += sm * kinv[L];
        }
    }
    z[tid] = zv;
    __syncthreads();
    if (tid < 64) {
        float acc = L1b[tid];
        for (int i = 0; i < 128; ++i) acc = fmaf(z[i], L1w[i * 64 + tid], acc);
        h1[tid] = fmaxf(acc, 0.0f);
    }
    __syncthreads();
    if (tid < 32) {
        float acc = L2b[tid];
        for (int i = 0; i < 64; ++i) acc = fmaf(h1[i], L2w[i * 32 + tid], acc);
        h2[tid] = fmaxf(acc, 0.0f);
    }
    __syncthreads();
    if (tid < 10) {
        float acc = L3b[tid];
        for (int i = 0; i < 32; ++i) acc = fmaf(h2[i], L3w[i * 10 + tid], acc);
        lg[tid] = acc;
    }
    __syncthreads();
    if (tid == 0) {
        float m = lg[0];
        for (int i = 1; i < 10; ++i) m = fmaxf(m, lg[i]);
        float s = 0.0f;
        for (int i = 0; i < 10; ++i) s += expf(lg[i] - m);
        lse = m + logf(s);
    }
    __syncthreads();
    if (tid < 10) out[g * 10 + tid] = lg[tid] - lse;
}

// ---------------- launcher ----------------
extern "C" void kernel_launch(void* const* d_in, const int* in_sizes, int n_in,
                              void* d_out, int out_size, void* d_ws, size_t ws_size,
                              hipStream_t stream) {
    const float* x    = (const float*)d_in[0];
    const int*   esrc = (const int*)d_in[1];
    const int*   edst = (const int*)d_in[2];
    const float* W [3] = {(const float*)d_in[3],  (const float*)d_in[7],  (const float*)d_in[11]};
    const float* bb[3] = {(const float*)d_in[4],  (const float*)d_in[8],  (const float*)d_in[12]};
    const float* Wp[3] = {(const float*)d_in[5],  (const float*)d_in[9],  (const float*)d_in[13]};
    const float* bp[3] = {(const float*)d_in[6],  (const float*)d_in[10], (const float*)d_in[14]};
    const float* L1w = (const float*)d_in[15];
    const float* L1b = (const float*)d_in[16];
    const float* L2w = (const float*)d_in[17];
    const float* L2b = (const float*)d_in[18];
    const float* L3w = (const float*)d_in[19];
    const float* L3b = (const float*)d_in[20];
    float* out = (float*)d_out;

    // workspace carve (words)
    float* fws   = (float*)d_ws;
    float* agg   = fws;                     // conv output h, BN_*64
    float* xw    = agg  + (size_t)BN_ * 64; // row-major pre-scaled xws
    float* dis   = xw   + (size_t)BN_ * 64; // B*n
    float* ps    = dis  + BN_;              // score messages, B*n
    float* ggate = ps   + BN_;              // gates per pooled row
    float* pz    = ggate + BN_;             // 3*B*NSEG*128 readout partials
    int*   perm   = (int*)(pz + 3 * B_ * NSEG * 128);
    int*   cum    = perm + BN_;             // orig node -> current local id (or -1)
    int*   srt    = cum + BN_;              // CSR: src ids grouped by dst
    int*   rowptr = srt + E_;               // B * (n+1)
    unsigned short* wfrag = (unsigned short*)(rowptr + B_ * (N_ + 1)); // 3*8192

    k_wprep3<<<3, 1024, 0, stream>>>(W[0], W[1], W[2], wfrag);

    const int ks_[3] = {820, 656, 525};   // ceil(0.8*1024), ceil(0.8*820), ceil(0.8*656)
    int n = N_;

    for (int L = 0; L < 3; ++L) {
        int rows = B_ * n;
        int k    = ks_[L];

        // CSR from original edges + cumulative node map (also computes dis)
        k_csr2<<<B_, 1024, 0, stream>>>(esrc, edst, (L == 0) ? nullptr : cum,
                                        srt, rowptr, dis, n);

        // xws = (gathered/gated h @ W) * dis via MFMA, row-major
        if (L == 0)
            k_xw_mfma<<<rows / 128, 256, 0, stream>>>(x, nullptr, nullptr,
                                                      wfrag, dis, xw, rows);
        else
            k_xw_mfma<<<rows / 128, 256, 0, stream>>>(agg, perm, ggate,
                                                      wfrag + (size_t)L * 8192, dis, xw, rows);

        // row-per-wave coalesced gather aggregation + bias/ReLU + score messages
        k_agg_gather<<<B_ * 4, 1024, 0, stream>>>(
            srt, rowptr, dis, xw, bb[L], Wp[L], agg, ps, n);

        // score aggregation + top-k + gates + cum update
        k_score_topk<<<B_, 1024, 0, stream>>>(srt, rowptr, dis, ps, bp[L], n, k,
                                              perm, ggate, cum, (L < 2) ? (L + 1) : 0);

        // segmented readout partials
        k_readout_seg<<<B_ * NSEG, 256, 0, stream>>>(agg, perm, ggate, k,
                                                     pz + (size_t)L * B_ * NSEG * 128);

        n = k;
    }

    k_mlp<<<B_, 128, 0, stream>>>(pz, L1w, L1b, L2w, L2b, L3w, L3b, out);
}

// Round 14
// 226.433 us; speedup vs baseline: 1.5527x; 1.5527x over previous
//
#include <hip/hip_runtime.h>
#include <math.h>

// Problem constants
constexpr int B_  = 128;
constexpr int N_  = 1024;
constexpr int E_  = 1048576;
constexpr int BN_ = B_ * N_;      // 131072
constexpr int EPG = E_ / B_;      // 8192 edges per graph (contiguous, fixed)
constexpr int NSEG = 16;          // readout segments per graph

typedef short v8s __attribute__((ext_vector_type(8)));
typedef float v4f __attribute__((ext_vector_type(4)));

__device__ __forceinline__ unsigned bf16_rne(unsigned u) {
    return (u + 0x7FFFu + ((u >> 16) & 1u)) >> 16;
}

// ---------------- per-graph CSR build from ORIGINAL edges + cumulative map ----------------
__global__ __launch_bounds__(1024) void k_csr2(
        const int* __restrict__ src, const int* __restrict__ dst,
        const int* __restrict__ cum,
        int* __restrict__ srt, int* __restrict__ rowptr,
        float* __restrict__ dis, int n) {
    __shared__ int cnt[1024];
    __shared__ int cur[1024];
    __shared__ int cums[1024];
    __shared__ int wsum[17];
    int g = blockIdx.x, tid = threadIdx.x;
    int gb   = g * N_;            // original node base
    int base = g * n;             // current node base
    const int eb = g * EPG;

    cums[tid] = cum ? cum[gb + tid] : tid;
    cnt[tid] = 0;
    __syncthreads();
    for (int t = tid; t < EPG; t += 1024) {
        int s = cums[src[eb + t] - gb];
        int d = cums[dst[eb + t] - gb];
        if ((s | d) >= 0) atomicAdd(&cnt[d], 1);
    }
    __syncthreads();

    int c = (tid < n) ? cnt[tid] : 0;
    int v = c;
    int lane = tid & 63, wv = tid >> 6;
    #pragma unroll
    for (int off = 1; off < 64; off <<= 1) {
        int t = __shfl_up(v, off, 64);
        if (lane >= off) v += t;
    }
    if (lane == 63) wsum[wv] = v;
    __syncthreads();
    if (tid == 0) {
        int run = 0;
        #pragma unroll
        for (int i = 0; i < 16; ++i) { int t = wsum[i]; wsum[i] = run; run += t; }
        wsum[16] = run;
    }
    __syncthreads();
    int excl = v - c + wsum[wv];
    if (tid < n) {
        cur[tid] = excl;
        rowptr[g * (n + 1) + tid] = excl;
        dis[base + tid] = rsqrtf((float)c + 1.0f);
    }
    if (tid == 0) rowptr[g * (n + 1) + n] = wsum[16];
    __syncthreads();

    for (int t = tid; t < EPG; t += 1024) {
        int s = cums[src[eb + t] - gb];
        int d = cums[dst[eb + t] - gb];
        if ((s | d) < 0) continue;
        int pos = atomicAdd(&cur[d], 1);
        srt[eb + pos] = s;
    }
}

// ---------------- W fragment prep for all 3 layers ----------------
__global__ __launch_bounds__(1024) void k_wprep3(
        const float* __restrict__ W0, const float* __restrict__ W1,
        const float* __restrict__ W2, unsigned short* __restrict__ wfall) {
    const float* W = (blockIdx.x == 0) ? W0 : (blockIdx.x == 1) ? W1 : W2;
    unsigned short* wf = wfall + (size_t)blockIdx.x * 8192;
    int t = threadIdx.x;
    int l  = t & 63;
    int kk = (t >> 6) & 1;
    int c  = (t >> 7) & 3;
    int p  = (t >> 9) & 1;
    int col = c * 16 + (l & 15);
    int kbase = kk * 32 + (l >> 4) * 8;
    unsigned short o[8];
    #pragma unroll
    for (int j = 0; j < 8; ++j) {
        float w = W[(kbase + j) * 64 + col];
        unsigned u  = __float_as_uint(w);
        unsigned hi = bf16_rne(u);
        if (p == 0) o[j] = (unsigned short)hi;
        else {
            float lo = w - __uint_as_float(hi << 16);
            o[j] = (unsigned short)bf16_rne(__float_as_uint(lo));
        }
    }
    uint4 v;
    v.x = o[0] | ((unsigned)o[1] << 16);
    v.y = o[2] | ((unsigned)o[3] << 16);
    v.z = o[4] | ((unsigned)o[5] << 16);
    v.w = o[6] | ((unsigned)o[7] << 16);
    *reinterpret_cast<uint4*>(wf + (size_t)t * 8) = v;
}

// ---------------- xws = (gather(h)*gate @ W) * dis via split-bf16 MFMA ----------------
// perm==NULL: direct rows (layer 0). Output quarter-plane xwq[(c*rows+r)*16+col].
__global__ __launch_bounds__(256) void k_xw_mfma(
        const float* __restrict__ h, const int* __restrict__ perm,
        const float* __restrict__ ggate, const unsigned short* __restrict__ wf,
        const float* __restrict__ dis, float* __restrict__ xwq, int rows) {
    __shared__ float hs[128][68];
    __shared__ float sdis[128];
    __shared__ int   lperm[128];
    __shared__ float lgate[128];
    int tid = threadIdx.x;
    int r0 = blockIdx.x * 128;

    if (perm) {
        if (tid < 128) { lperm[tid] = perm[r0 + tid]; lgate[tid] = ggate[r0 + tid]; }
        __syncthreads();
        for (int i = tid; i < 128 * 16; i += 256) {
            int row = i >> 4, s = i & 15;
            float4 v = *reinterpret_cast<const float4*>(h + (size_t)lperm[row] * 64 + s * 4);
            float gt = lgate[row];
            v.x *= gt; v.y *= gt; v.z *= gt; v.w *= gt;
            *reinterpret_cast<float4*>(&hs[row][s * 4]) = v;
        }
    } else {
        for (int i = tid; i < 128 * 16; i += 256) {
            int row = i >> 4, s = i & 15;
            float4 v = *reinterpret_cast<const float4*>(h + (size_t)(r0 + row) * 64 + s * 4);
            *reinterpret_cast<float4*>(&hs[row][s * 4]) = v;
        }
    }
    if (tid < 128) sdis[tid] = dis[r0 + tid];

    int lane = tid & 63;
    v8s wh[4][2], wl[4][2];
    #pragma unroll
    for (int c = 0; c < 4; ++c) {
        #pragma unroll
        for (int kk = 0; kk < 2; ++kk) {
            wh[c][kk] = *reinterpret_cast<const v8s*>(wf + (((size_t)((0*4 + c)*2 + kk))*64 + lane)*8);
            wl[c][kk] = *reinterpret_cast<const v8s*>(wf + (((size_t)((1*4 + c)*2 + kk))*64 + lane)*8);
        }
    }
    __syncthreads();

    int wave = tid >> 6;
    int m = lane & 15, b = lane >> 4;
    #pragma unroll
    for (int t = 0; t < 2; ++t) {
        int lr0 = (wave * 2 + t) * 16;
        float f[16];
        *reinterpret_cast<float4*>(f)      = *reinterpret_cast<const float4*>(&hs[lr0 + m][b * 8]);
        *reinterpret_cast<float4*>(f + 4)  = *reinterpret_cast<const float4*>(&hs[lr0 + m][b * 8 + 4]);
        *reinterpret_cast<float4*>(f + 8)  = *reinterpret_cast<const float4*>(&hs[lr0 + m][32 + b * 8]);
        *reinterpret_cast<float4*>(f + 12) = *reinterpret_cast<const float4*>(&hs[lr0 + m][32 + b * 8 + 4]);
        v8s ah[2], al[2];
        #pragma unroll
        for (int ch = 0; ch < 2; ++ch) {
            #pragma unroll
            for (int j = 0; j < 8; ++j) {
                float x = f[ch * 8 + j];
                unsigned u  = __float_as_uint(x);
                unsigned hi = bf16_rne(u);
                float lo = x - __uint_as_float(hi << 16);
                ah[ch][j] = (short)hi;
                al[ch][j] = (short)bf16_rne(__float_as_uint(lo));
            }
        }
        float dv[4];
        #pragma unroll
        for (int reg = 0; reg < 4; ++reg) dv[reg] = sdis[lr0 + b * 4 + reg];

        #pragma unroll
        for (int c = 0; c < 4; ++c) {
            v4f acc = {0.f, 0.f, 0.f, 0.f};
            acc = __builtin_amdgcn_mfma_f32_16x16x32_bf16(ah[0], wh[c][0], acc, 0, 0, 0);
            acc = __builtin_amdgcn_mfma_f32_16x16x32_bf16(ah[1], wh[c][1], acc, 0, 0, 0);
            acc = __builtin_amdgcn_mfma_f32_16x16x32_bf16(al[0], wh[c][0], acc, 0, 0, 0);
            acc = __builtin_amdgcn_mfma_f32_16x16x32_bf16(al[1], wh[c][1], acc, 0, 0, 0);
            acc = __builtin_amdgcn_mfma_f32_16x16x32_bf16(ah[0], wl[c][0], acc, 0, 0, 0);
            acc = __builtin_amdgcn_mfma_f32_16x16x32_bf16(ah[1], wl[c][1], acc, 0, 0, 0);
            acc = __builtin_amdgcn_mfma_f32_16x16x32_bf16(al[0], wl[c][0], acc, 0, 0, 0);
            acc = __builtin_amdgcn_mfma_f32_16x16x32_bf16(al[1], wl[c][1], acc, 0, 0, 0);
            #pragma unroll
            for (int reg = 0; reg < 4; ++reg) {
                int grow = r0 + lr0 + b * 4 + reg;
                xwq[((size_t)c * rows + grow) * 16 + m] = acc[reg] * dv[reg];
            }
        }
    }
}

// ---------------- CSR edge aggregation + bias/ReLU + score-conv partials ----------------
__global__ __launch_bounds__(1024) void k_agg_csr(
        const int* __restrict__ srt, const int* __restrict__ rowptr,
        const float* __restrict__ dis, const float* __restrict__ xwq,
        const float* __restrict__ bias, const float* __restrict__ Wp,
        float* __restrict__ hout, float* __restrict__ sxwsq,
        int n, int rows) {
    extern __shared__ float lds[];
    float* xs  = lds;                       // n * 20
    int* lsrt  = (int*)(lds + n * 20);      // EPG
    int* lrp   = lsrt + EPG;                // n + 1
    int g = blockIdx.x >> 2, q = blockIdx.x & 3;
    int foff = q * 16;
    int tid  = threadIdx.x;
    int base = g * n;
    const float* plane = xwq + ((size_t)q * rows + base) * 16;

    for (int i = tid; i < n * 4; i += 1024) {
        int row = i >> 2, sub = i & 3;
        float4 v = *reinterpret_cast<const float4*>(plane + row * 16 + sub * 4);
        *reinterpret_cast<float4*>(xs + row * 20 + sub * 4) = v;
    }
    for (int i = tid; i <= n; i += 1024) lrp[i] = rowptr[g * (n + 1) + i];
    __syncthreads();
    int total = lrp[n];
    const int* gsrt = srt + g * EPG;
    for (int i = tid; i < total; i += 1024) lsrt[i] = gsrt[i];
    __syncthreads();

    int sub = tid & 3;
    float4 b   = *reinterpret_cast<const float4*>(bias + foff + sub * 4);
    float4 wp4 = *reinterpret_cast<const float4*>(Wp   + foff + sub * 4);
    for (int row = tid >> 2; row < n; row += 256) {
        int s0 = lrp[row], s1 = lrp[row + 1];
        float4 acc = *reinterpret_cast<const float4*>(xs + row * 20 + sub * 4); // self-loop
        for (int j = s0; j < s1; ++j) {
            int s = lsrt[j];
            const float4 v = *reinterpret_cast<const float4*>(xs + s * 20 + sub * 4);
            acc.x += v.x; acc.y += v.y; acc.z += v.z; acc.w += v.w;
        }
        float dsc = dis[base + row];
        float4 o;
        o.x = fmaxf(fmaf(dsc, acc.x, b.x), 0.0f);
        o.y = fmaxf(fmaf(dsc, acc.y, b.y), 0.0f);
        o.z = fmaxf(fmaf(dsc, acc.z, b.z), 0.0f);
        o.w = fmaxf(fmaf(dsc, acc.w, b.w), 0.0f);
        *reinterpret_cast<float4*>(hout + (size_t)(base + row) * 64 + foff + sub * 4) = o;
        // score-conv partial over this 16-feature quarter
        float part = o.x * wp4.x + o.y * wp4.y + o.z * wp4.z + o.w * wp4.w;
        part += __shfl_xor(part, 1, 64);
        part += __shfl_xor(part, 2, 64);
        if (sub == 0) sxwsq[(size_t)q * BN_ + base + row] = part;
    }
}

// ---------------- fused score aggregation + top-k + gates + cum update ----------------
// 1 block per graph, 1024 threads. do_compose: 0 none, 1 identity-init, 2 chained.
__global__ __launch_bounds__(1024) void k_score_topk(
        const int* __restrict__ srt, const int* __restrict__ rowptr,
        const float* __restrict__ dis, const float* __restrict__ sxwsq,
        const float* __restrict__ bp, int n, int k,
        int* __restrict__ perm, float* __restrict__ ggate,
        int* __restrict__ cum, int do_compose) {
    __shared__ float xs[1024];
    __shared__ int   lrp[1025];
    __shared__ int   lsrt[EPG];              // re-used as sort keys after CSR phase
    unsigned long long* keys = (unsigned long long*)lsrt;
    int* mark = (int*)xs;                    // re-used after sagg phase
    int g = blockIdx.x, tid = threadIdx.x;
    int base = g * n;
    float bp0 = bp[0];

    if (tid < n) {
        float s0 = sxwsq[0 * (size_t)BN_ + base + tid] + sxwsq[1 * (size_t)BN_ + base + tid]
                 + sxwsq[2 * (size_t)BN_ + base + tid] + sxwsq[3 * (size_t)BN_ + base + tid];
        xs[tid] = s0 * dis[base + tid];      // pre-scaled neighbor/self message
    }
    for (int i = tid; i <= n; i += 1024) lrp[i] = rowptr[g * (n + 1) + i];
    __syncthreads();
    int total = lrp[n];
    for (int i = tid; i < total; i += 1024) lsrt[i] = srt[g * EPG + i];
    __syncthreads();

    float sag = 0.0f;
    if (tid < n) {
        float acc = xs[tid];                 // self loop
        int s1 = lrp[tid + 1];
        for (int j = lrp[tid]; j < s1; ++j) acc += xs[lsrt[j]];
        sag = dis[base + tid] * acc + bp0;   // score incl. bias
    }
    __syncthreads();                          // done with xs + lsrt contents

    {
        unsigned long long kv = 0ull;
        if (tid < n) {
            unsigned u  = __float_as_uint(sag);
            unsigned mk = (u & 0x80000000u) ? ~u : (u | 0x80000000u);
            kv = ((unsigned long long)mk << 32) | (unsigned)tid;
        }
        keys[tid] = kv;
        mark[tid] = -1;
    }

    for (int size = 2; size <= 1024; size <<= 1) {
        for (int stride = size >> 1; stride > 0; stride >>= 1) {
            __syncthreads();
            if (tid < 512) {
                int a  = ((tid / stride) * (stride << 1)) + (tid & (stride - 1));
                int bx = a + stride;
                bool asc = ((a & size) == 0);
                unsigned long long ka = keys[a], kb = keys[bx];
                bool sw = asc ? (ka > kb) : (ka < kb);
                if (sw) { keys[a] = kb; keys[bx] = ka; }
            }
        }
    }
    __syncthreads();

    if (tid < k) {
        int j = tid;                          // k <= 1024: one thread per slot
        unsigned long long kv = keys[1023 - j];
        int local   = (int)(kv & 0xFFFFFFFFull);
        unsigned mk = (unsigned)(kv >> 32);
        unsigned u  = (mk & 0x80000000u) ? (mk ^ 0x80000000u) : ~mk;
        int newg = g * k + j;
        perm[newg]  = base + local;
        ggate[newg] = tanhf(__uint_as_float(u));
        mark[local] = j;
    }
    __syncthreads();
    if (do_compose) {
        int gb = g * N_;
        int c = (do_compose == 1) ? tid : cum[gb + tid];
        cum[gb + tid] = (c >= 0) ? mark[c] : -1;
    }
}

// ---------------- segmented readout (max + sum partials), no materialization ----------------
__global__ __launch_bounds__(256) void k_readout_seg(
        const float* __restrict__ h, const int* __restrict__ perm,
        const float* __restrict__ ggate, int k, float* __restrict__ pz) {
    int g = blockIdx.x / NSEG, seg = blockIdx.x % NSEG;
    int ck = (k + NSEG - 1) / NSEG;
    int j0 = seg * ck;
    int j1 = min(k, j0 + ck);
    __shared__ float gate[64];
    __shared__ int   lperm[64];
    int tid = threadIdx.x;
    for (int j = j0 + tid; j < j1; j += 256) {
        lperm[j - j0] = perm[g * k + j];
        gate[j - j0]  = ggate[g * k + j];
    }
    __syncthreads();
    int lane = tid & 63, w = tid >> 6;
    float mx = -INFINITY, sm = 0.0f;
    for (int j = j0 + w; j < j1; j += 4) {
        float v = h[(size_t)lperm[j - j0] * 64 + lane] * gate[j - j0];
        mx = fmaxf(mx, v); sm += v;
    }
    __shared__ float smx[4][64], ssm[4][64];
    smx[w][lane] = mx; ssm[w][lane] = sm;
    __syncthreads();
    if (w == 0) {
        #pragma unroll
        for (int i = 1; i < 4; ++i) { mx = fmaxf(mx, smx[i][lane]); sm += ssm[i][lane]; }
        float* p = pz + ((size_t)g * NSEG + seg) * 128;
        p[lane]      = mx;
        p[64 + lane] = sm;
    }
}

// ---------------- MLP head: reduce pz over layers/segments + log_softmax ----------------
__global__ __launch_bounds__(128) void k_mlp(const float* __restrict__ pz,
                      const float* __restrict__ L1w, const float* __restrict__ L1b,
                      const float* __restrict__ L2w, const float* __restrict__ L2b,
                      const float* __restrict__ L3w, const float* __restrict__ L3b,
                      float* __restrict__ out) {
    __shared__ float z[128], h1[64], h2[32], lg[10], lse;
    int g = blockIdx.x, tid = threadIdx.x;
    const float kinv[3] = {1.0f / 820.0f, 1.0f / 656.0f, 1.0f / 525.0f};
    float zv = 0.0f;
    if (tid < 64) {
        #pragma unroll
        for (int L = 0; L < 3; ++L) {
            const float* p = pz + (((size_t)L * B_ + g) * NSEG) * 128;
            float mx = -INFINITY;
            #pragma unroll
            for (int s = 0; s < NSEG; ++s) mx = fmaxf(mx, p[s * 128 + tid]);
            zv += mx;
        }
    } else {
        int f = tid - 64;
        #pragma unroll
        for (int L = 0; L < 3; ++L) {
            const float* p = pz + (((size_t)L * B_ + g) * NSEG) * 128;
            float sm = 0.0f;
            #pragma unroll
            for (int s = 0; s < NSEG; ++s) sm += p[s * 128 + 64 + f];
            zv += sm * kinv[L];
        }
    }
    z[tid] = zv;
    __syncthreads();
    if (tid < 64) {
        float acc = L1b[tid];
        for (int i = 0; i < 128; ++i) acc = fmaf(z[i], L1w[i * 64 + tid], acc);
        h1[tid] = fmaxf(acc, 0.0f);
    }
    __syncthreads();
    if (tid < 32) {
        float acc = L2b[tid];
        for (int i = 0; i < 64; ++i) acc = fmaf(h1[i], L2w[i * 32 + tid], acc);
        h2[tid] = fmaxf(acc, 0.0f);
    }
    __syncthreads();
    if (tid < 10) {
        float acc = L3b[tid];
        for (int i = 0; i < 32; ++i) acc = fmaf(h2[i], L3w[i * 10 + tid], acc);
        lg[tid] = acc;
    }
    __syncthreads();
    if (tid == 0) {
        float m = lg[0];
        for (int i = 1; i < 10; ++i) m = fmaxf(m, lg[i]);
        float s = 0.0f;
        for (int i = 0; i < 10; ++i) s += expf(lg[i] - m);
        lse = m + logf(s);
    }
    __syncthreads();
    if (tid < 10) out[g * 10 + tid] = lg[tid] - lse;
}

// ---------------- launcher ----------------
extern "C" void kernel_launch(void* const* d_in, const int* in_sizes, int n_in,
                              void* d_out, int out_size, void* d_ws, size_t ws_size,
                              hipStream_t stream) {
    const float* x    = (const float*)d_in[0];
    const int*   esrc = (const int*)d_in[1];
    const int*   edst = (const int*)d_in[2];
    const float* W [3] = {(const float*)d_in[3],  (const float*)d_in[7],  (const float*)d_in[11]};
    const float* bb[3] = {(const float*)d_in[4],  (const float*)d_in[8],  (const float*)d_in[12]};
    const float* Wp[3] = {(const float*)d_in[5],  (const float*)d_in[9],  (const float*)d_in[13]};
    const float* bp[3] = {(const float*)d_in[6],  (const float*)d_in[10], (const float*)d_in[14]};
    const float* L1w = (const float*)d_in[15];
    const float* L1b = (const float*)d_in[16];
    const float* L2w = (const float*)d_in[17];
    const float* L2b = (const float*)d_in[18];
    const float* L3w = (const float*)d_in[19];
    const float* L3b = (const float*)d_in[20];
    float* out = (float*)d_out;

    // workspace carve (words)
    float* fws   = (float*)d_ws;
    float* agg   = fws;                     // conv output h, BN_*64
    float* xwq   = agg  + (size_t)BN_ * 64; // quarter-plane xws
    float* dis   = xwq  + (size_t)BN_ * 64; // B*n
    float* sxwsq = dis  + BN_;              // 4 quarter score partial planes
    float* ggate = sxwsq + 4 * (size_t)BN_; // gates per pooled row
    float* pz    = ggate + BN_;             // 3*B*NSEG*128 readout partials
    int*   perm   = (int*)(pz + 3 * B_ * NSEG * 128);
    int*   cum    = perm + BN_;             // orig node -> current local id (or -1)
    int*   srt    = cum + BN_;              // CSR: src ids grouped by dst
    int*   rowptr = srt + E_;               // B * (n+1)
    unsigned short* wfrag = (unsigned short*)(rowptr + B_ * (N_ + 1)); // 3*8192

    // allow >64KB dynamic LDS for the aggregation kernel (max n=1024: 118788B)
    hipFuncSetAttribute(reinterpret_cast<const void*>(k_agg_csr),
                        hipFuncAttributeMaxDynamicSharedMemorySize,
                        (1024 * 20 + EPG + 1025) * 4);

    k_wprep3<<<3, 1024, 0, stream>>>(W[0], W[1], W[2], wfrag);

    const int ks_[3] = {820, 656, 525};   // ceil(0.8*1024), ceil(0.8*820), ceil(0.8*656)
    int n = N_;

    for (int L = 0; L < 3; ++L) {
        int rows = B_ * n;
        int k    = ks_[L];

        // CSR from original edges + cumulative node map (also computes dis)
        k_csr2<<<B_, 1024, 0, stream>>>(esrc, edst, (L == 0) ? nullptr : cum,
                                        srt, rowptr, dis, n);

        // xws = (gathered/gated h @ W) * dis via MFMA, quarter layout
        if (L == 0)
            k_xw_mfma<<<rows / 128, 256, 0, stream>>>(x, nullptr, nullptr,
                                                      wfrag, dis, xwq, rows);
        else
            k_xw_mfma<<<rows / 128, 256, 0, stream>>>(agg, perm, ggate,
                                                      wfrag + (size_t)L * 8192, dis, xwq, rows);

        // CSR aggregation + bias/ReLU + score-conv partials
        k_agg_csr<<<B_ * 4, 1024, (size_t)(n * 20 + EPG + n + 1) * 4, stream>>>(
            srt, rowptr, dis, xwq, bb[L], Wp[L], agg, sxwsq, n, rows);

        // score aggregation + top-k + gates + cum update
        k_score_topk<<<B_, 1024, 0, stream>>>(srt, rowptr, dis, sxwsq, bp[L], n, k,
                                              perm, ggate, cum, (L < 2) ? (L + 1) : 0);

        // segmented readout partials
        k_readout_seg<<<B_ * NSEG, 256, 0, stream>>>(agg, perm, ggate, k,
                                                     pz + (size_t)L * B_ * NSEG * 128);

        n = k;
    }

    k_mlp<<<B_, 128, 0, stream>>>(pz, L1w, L1b, L2w, L2b, L3w, L3b, out);
}